// Round 2
// baseline (1706.962 us; speedup 1.0000x reference)
//
#include <hip/hip_runtime.h>
#include <math.h>

// One block per sample (grid 256), 1024 threads = (a in [0,512)) x (h in {0,1}).
// Thread (a,h) owns d-positions [32h, 32h+32). All LNs are block-local.
// Dilated conv via rolling 5-slot register windows; base2->base3 updated
// in-place in ONE [B][D][A] f4 buffer. Cross-half base2 boundary (d in
// [28,36)) exchanged through LDS bnd[]; phase-D boundary reads hit global
// after a reduction barrier. GELU = tanh-form sigmoid (exp2+rcp), ~6 VALU.

#define EPS_LN 1e-5f
typedef float4 f4;

__device__ __forceinline__ float gelu_f(float v) {
    // x * sigmoid(1.5957691*(x + 0.044715 x^3)), exp2 domain
    float t = v * fmaf(0.10294324f, v * v, 2.30220822f);
    float e = __builtin_amdgcn_exp2f(-t);
    return v * __builtin_amdgcn_rcpf(1.0f + e);
}

// y[o] = dilated conv taps: a=x[d-2], c=x[d], e=x[d+2]; wd (4,4,1,3) flat
__device__ __forceinline__ void conv4(const f4 a, const f4 c, const f4 e,
                                      const float* __restrict__ wd, float y[4]) {
#pragma unroll
    for (int o = 0; o < 4; ++o) {
        const float* wv = wd + o * 12;
        y[o] = fmaf(a.x, wv[0], fmaf(c.x, wv[1], fmaf(e.x, wv[2],
               fmaf(a.y, wv[3], fmaf(c.y, wv[4], fmaf(e.y, wv[5],
               fmaf(a.z, wv[6], fmaf(c.z, wv[7], fmaf(e.z, wv[8],
               fmaf(a.w, wv[9], fmaf(c.w, wv[10], e.w * wv[11])))))))))));
    }
}

__device__ __forceinline__ void block_red2(float& x, float& y, float* red,
                                           float* bc, int tid) {
#pragma unroll
    for (int off = 32; off > 0; off >>= 1) {
        x += __shfl_down(x, off, 64);
        y += __shfl_down(y, off, 64);
    }
    const int w = tid >> 6;                 // 16 waves
    if ((tid & 63) == 0) { red[w] = x; red[16 + w] = y; }
    __syncthreads();
    if (tid == 0) {
        float sx = 0.f, sy = 0.f;
#pragma unroll
        for (int i = 0; i < 16; ++i) { sx += red[i]; sy += red[16 + i]; }
        bc[0] = sx; bc[1] = sy;
    }
    __syncthreads();
    x = bc[0]; y = bc[1];
}

__global__ __launch_bounds__(1024, 4)
void tcn_fused(const float* __restrict__ sIn, const float* __restrict__ wIn,
               const float* __restrict__ w1d, const float* __restrict__ w1p,
               const float* __restrict__ w2d, const float* __restrict__ w2p,
               const float* __restrict__ w3d, const float* __restrict__ w3p,
               const float* __restrict__ cw,  const float* __restrict__ c2w,
               const float* __restrict__ c3w, float* __restrict__ out,
               f4* __restrict__ baseT) {
    const int b   = blockIdx.x;
    const int tid = threadIdx.x;
    const int a   = tid & 511;
    const int h   = tid >> 9;               // wave-uniform (waves 0-7: h=0)
    const int d0  = h << 5;

    __shared__ float red[32];
    __shared__ float bcs[2];
    __shared__ float Klds[16];
    __shared__ f4    bnd[512][8];           // base2[d] for d in [28,36), per a

    // K[o] = sum_{co,d} c2w[o,co,d] * (sum_j cw[co*12+j])
    if (tid < 16) {
        float k = 0.f;
        for (int co = 0; co < 4; ++co) {
            float csum = 0.f;
            for (int j = 0; j < 12; ++j) csum += cw[co * 12 + j];
            const float* p = c2w + tid * 256 + co * 64;
            float t = 0.f;
            for (int d = 0; d < 64; ++d) t += p[d];
            k = fmaf(csum, t, k);
        }
        Klds[tid] = k;
    }

    const f4* s4 = (const f4*)sIn;
    const size_t srow = ((size_t)b * 512 + a) * 64;      // s: [b][a][d]
    const size_t bcol = (size_t)b * 32768 + a;           // base: [b][d][a]
    const f4 z4 = make_float4(0.f, 0.f, 0.f, 0.f);
    const float NY = 131072.f;                           // 4*512*64

    auto ldS = [&](int q) -> f4 { return (q >= 0 && q < 64) ? s4[srow + q] : z4; };
    auto ldB = [&](int q) -> f4 { return (q >= 0 && q < 64) ? baseT[bcol + (size_t)q * 512] : z4; };
    auto ldB2 = [&](int q) -> f4 {          // base2 with LDS boundary exchange
        if (q < 0 || q >= 64) return z4;
        if (q >= d0 && q < d0 + 32) return baseT[bcol + (size_t)q * 512];
        return bnd[a][q - 28];              // foreign: q in [28,36)
    };

    // ---------- Phase A: stats of y1 = conv(s) over own positions ----------
    float s1 = 0.f, s2 = 0.f;
    {
        f4 wA = ldS(d0 - 2), wB = ldS(d0 - 1), wC = ldS(d0), wD = ldS(d0 + 1), wE;
#pragma unroll 4
        for (int e = d0; e < d0 + 32; ++e) {
            wE = ldS(e + 2);
            float y[4]; conv4(wA, wC, wE, w1d, y);
#pragma unroll
            for (int o = 0; o < 4; ++o) { s1 += y[o]; s2 = fmaf(y[o], y[o], s2); }
            wA = wB; wB = wC; wC = wD; wD = wE;
        }
    }
    block_red2(s1, s2, red, bcs, tid);
    const float m1 = s1 / NY;
    const float r1 = rsqrtf(s2 / NY - m1 * m1 + EPS_LN);

    float t16a[16];
#pragma unroll
    for (int o = 0; o < 16; ++o) t16a[o] = 0.f;
    float cs1 = 0.f, cs2 = 0.f;

    // ---------- Phase B: x1 / base2 (store own), y2 stats ----------
    // stream j in [0,40): q=d0-4+j s-load; c=q-2 base2 pos; e=q-4 y2 pos
    float q1 = 0.f, q2 = 0.f;
    {
        f4 sA = z4, sB = z4, sC = z4, sD = z4, sE;
        f4 bA = z4, bB = z4, bC = z4, bD = z4, bE;
#pragma unroll 5
        for (int j = 0; j < 40; ++j) {
            const int q = d0 - 4 + j;
            sE = ldS(q);
            const int c = q - 2;
            f4 nb = z4;
            if (j >= 4 && c >= 0 && c < 64) {
                float y[4]; conv4(sA, sC, sE, w1d, y);
#pragma unroll
                for (int o = 0; o < 4; ++o) y[o] = (y[o] - m1) * r1;
                float g[4];
#pragma unroll
                for (int o = 0; o < 4; ++o) {
                    float zz = fmaf(y[0], w1p[o*4+0], fmaf(y[1], w1p[o*4+1],
                               fmaf(y[2], w1p[o*4+2], y[3] * w1p[o*4+3])));
                    g[o] = gelu_f(zz);
                }
                nb.x = sC.x + g[0]; nb.y = sC.y + g[1];
                nb.z = sC.z + g[2]; nb.w = sC.w + g[3];
                if (c >= d0 && c < d0 + 32) {            // own position
#pragma unroll
                    for (int o = 0; o < 4; ++o) { cs1 += g[o]; cs2 = fmaf(g[o], g[o], cs2); }
                    float u[4];
#pragma unroll
                    for (int co = 0; co < 4; ++co)
                        u[co] = fmaf(g[0], cw[co*12+0], fmaf(g[1], cw[co*12+1],
                                fmaf(g[2], cw[co*12+2], g[3] * cw[co*12+3])));
#pragma unroll
                    for (int o = 0; o < 16; ++o) {
                        const float* p = c2w + o * 256 + c;
                        t16a[o] = fmaf(u[0], p[0], fmaf(u[1], p[64],
                                  fmaf(u[2], p[128], fmaf(u[3], p[192], t16a[o]))));
                    }
                    baseT[bcol + (size_t)c * 512] = nb;
                    if (c >= 28 && c < 36) bnd[a][c - 28] = nb;
                }
            }
            bE = nb;
            if (j >= 8) {                                // e in [d0, d0+32)
                float y2[4]; conv4(bA, bC, bE, w2d, y2);
#pragma unroll
                for (int o = 0; o < 4; ++o) { q1 += y2[o]; q2 = fmaf(y2[o], y2[o], q2); }
            }
            sA = sB; sB = sC; sC = sD; sD = sE;
            bA = bB; bB = bC; bC = bD; bD = bE;
        }
    }
    block_red2(q1, q2, red, bcs, tid);                   // barrier: bnd/base2 ready
    const float m2s = q1 / NY;
    const float r2s = rsqrtf(q2 / NY - m2s * m2s + EPS_LN);

    // ---------- Phase C: x2 / base3 (in-place), y3 stats ----------
    float q31 = 0.f, q32 = 0.f;
    {
        f4 gA = z4, gB = z4, gC = z4, gD = z4, gE;
        f4 hA = z4, hB = z4, hC = z4, hD = z4, hE;
#pragma unroll 5
        for (int j = 0; j < 40; ++j) {
            const int q = d0 - 4 + j;
            gE = ldB2(q);
            const int c = q - 2;
            f4 nb = z4;
            if (j >= 4 && c >= 0 && c < 64) {
                float y[4]; conv4(gA, gC, gE, w2d, y);
#pragma unroll
                for (int o = 0; o < 4; ++o) y[o] = (y[o] - m2s) * r2s;
                float g[4];
#pragma unroll
                for (int o = 0; o < 4; ++o) {
                    float zz = fmaf(y[0], w2p[o*4+0], fmaf(y[1], w2p[o*4+1],
                               fmaf(y[2], w2p[o*4+2], y[3] * w2p[o*4+3])));
                    g[o] = gelu_f(zz);
                }
                nb.x = gC.x + g[0]; nb.y = gC.y + g[1];
                nb.z = gC.z + g[2]; nb.w = gC.w + g[3];
                if (c >= d0 && c < d0 + 32) {
#pragma unroll
                    for (int o = 0; o < 4; ++o) { cs1 += g[o]; cs2 = fmaf(g[o], g[o], cs2); }
                    float u[4];
#pragma unroll
                    for (int co = 0; co < 4; ++co)
                        u[co] = fmaf(g[0], cw[co*12+4], fmaf(g[1], cw[co*12+5],
                                fmaf(g[2], cw[co*12+6], g[3] * cw[co*12+7])));
#pragma unroll
                    for (int o = 0; o < 16; ++o) {
                        const float* p = c2w + o * 256 + c;
                        t16a[o] = fmaf(u[0], p[0], fmaf(u[1], p[64],
                                  fmaf(u[2], p[128], fmaf(u[3], p[192], t16a[o]))));
                    }
                    baseT[bcol + (size_t)c * 512] = nb;  // in-place, read-before-write
                }
            }
            hE = nb;
            if (j >= 8) {
                float y3[4]; conv4(hA, hC, hE, w3d, y3);
#pragma unroll
                for (int o = 0; o < 4; ++o) { q31 += y3[o]; q32 = fmaf(y3[o], y3[o], q32); }
            }
            gA = gB; gB = gC; gC = gD; gD = gE;
            hA = hB; hB = hC; hC = hD; hD = hE;
        }
    }
    block_red2(q31, q32, red, bcs, tid);                 // barrier: base3 ready
    const float m3s = q31 / NY;
    const float r3s = rsqrtf(q32 / NY - m3s * m3s + EPS_LN);

    // ---------- Phase D: x3 (reload base3, incl. neighbor boundary) ----------
    {
        f4 wA = ldB(d0 - 2), wB = ldB(d0 - 1), wC = ldB(d0), wD = ldB(d0 + 1), wE;
#pragma unroll 4
        for (int e = d0; e < d0 + 32; ++e) {
            wE = ldB(e + 2);
            float y[4]; conv4(wA, wC, wE, w3d, y);
#pragma unroll
            for (int o = 0; o < 4; ++o) y[o] = (y[o] - m3s) * r3s;
            float g[4];
#pragma unroll
            for (int o = 0; o < 4; ++o) {
                float zz = fmaf(y[0], w3p[o*4+0], fmaf(y[1], w3p[o*4+1],
                           fmaf(y[2], w3p[o*4+2], y[3] * w3p[o*4+3])));
                g[o] = gelu_f(zz);
            }
#pragma unroll
            for (int o = 0; o < 4; ++o) { cs1 += g[o]; cs2 = fmaf(g[o], g[o], cs2); }
            float u[4];
#pragma unroll
            for (int co = 0; co < 4; ++co)
                u[co] = fmaf(g[0], cw[co*12+8], fmaf(g[1], cw[co*12+9],
                        fmaf(g[2], cw[co*12+10], g[3] * cw[co*12+11])));
#pragma unroll
            for (int o = 0; o < 16; ++o) {
                const float* p = c2w + o * 256 + e;
                t16a[o] = fmaf(u[0], p[0], fmaf(u[1], p[64],
                          fmaf(u[2], p[128], fmaf(u[3], p[192], t16a[o]))));
            }
            wA = wB; wB = wC; wC = wD; wD = wE;
        }
    }

    // ---------- concat LN over [12,A,D] ----------
    block_red2(cs1, cs2, red, bcs, tid);
    const float NC = 393216.f;                           // 12*512*64
    const float mcat = cs1 / NC;
    const float rcat = rsqrtf(cs2 / NC - mcat * mcat + EPS_LN);

    // combine t16a halves via LDS (reuse bnd memory; stride 17 = conflict-free)
    float* t16s = (float*)bnd;
    if (h == 1) {
#pragma unroll
        for (int o = 0; o < 16; ++o) t16s[a * 17 + o] = t16a[o];
    }
    __syncthreads();

    float tv[16];
    float p1 = 0.f, p2 = 0.f;
    if (h == 0) {
#pragma unroll
        for (int o = 0; o < 16; ++o) {
            float T = t16a[o] + t16s[a * 17 + o];
            float v = rcat * (T - mcat * Klds[o]);
            tv[o] = v; p1 += v; p2 = fmaf(v, v, p2);
        }
    }
    block_red2(p1, p2, red, bcs, tid);
    const float m16 = p1 / 8192.f;
    const float r16 = rsqrtf(p2 / 8192.f - m16 * m16 + EPS_LN);

    float v = 0.f, f1 = 0.f, f2 = 0.f;
    if (h == 0) {
        v = wIn[(size_t)b * 512 + a] * c3w[16];
#pragma unroll
        for (int o = 0; o < 16; ++o) v = fmaf((tv[o] - m16) * r16, c3w[o], v);
        f1 = v; f2 = v * v;
    }
    block_red2(f1, f2, red, bcs, tid);
    const float mA = f1 / 512.f;
    const float rA = rsqrtf(f2 / 512.f - mA * mA + EPS_LN);

    if (h == 0) out[(size_t)b * 512 + a] = (v - mA) * rA;
}

extern "C" void kernel_launch(void* const* d_in, const int* in_sizes, int n_in,
                              void* d_out, int out_size, void* d_ws, size_t ws_size,
                              hipStream_t stream) {
    const float* s   = (const float*)d_in[0];
    const float* w   = (const float*)d_in[1];
    const float* w1d = (const float*)d_in[2];
    const float* w1p = (const float*)d_in[3];
    const float* w2d = (const float*)d_in[4];
    const float* w2p = (const float*)d_in[5];
    const float* w3d = (const float*)d_in[6];
    const float* w3p = (const float*)d_in[7];
    const float* cw  = (const float*)d_in[8];
    const float* c2w = (const float*)d_in[9];
    const float* c3w = (const float*)d_in[10];
    tcn_fused<<<dim3(256), dim3(1024), 0, stream>>>(
        s, w, w1d, w1p, w2d, w2p, w3d, w3p, cw, c2w, c3w,
        (float*)d_out, (f4*)d_ws);
}

// Round 3
// 674.094 us; speedup vs baseline: 2.5322x; 2.5322x over previous
//
#include <hip/hip_runtime.h>
#include <math.h>

// Multi-kernel TCN: phases split at LN-reduction boundaries; stream ordering
// replaces in-kernel barriers. Per-sample stats flow through per-block partial
// buffers (all written before read -> safe under ws re-poisoning). Every
// kernel is SINGLE rolling-window (state ~70 regs; the R2 dual-window variant
// spilled at the 128-reg budget -> 4.4 GB scratch traffic). Base tensor is
// bf16-packed ushort4 [B][D][A] (64 MB, coalesced across a, L3-resident).
// Grid 512 x 256 threads (thread = full d-column of one row a).

#define EPS_LN 1e-5f
typedef float4 f4;

__device__ __forceinline__ float gelu_f(float v) {
    // x * sigmoid(1.5957691*(x + 0.044715 x^3)) in exp2 domain, ~6 VALU
    float t = v * fmaf(0.10294324f, v * v, 2.30220822f);
    float e = __builtin_amdgcn_exp2f(-t);
    return v * __builtin_amdgcn_rcpf(1.0f + e);
}

__device__ __forceinline__ void conv4(const f4 a, const f4 c, const f4 e,
                                      const float* __restrict__ wd, float y[4]) {
#pragma unroll
    for (int o = 0; o < 4; ++o) {
        const float* wv = wd + o * 12;
        y[o] = fmaf(a.x, wv[0], fmaf(c.x, wv[1], fmaf(e.x, wv[2],
               fmaf(a.y, wv[3], fmaf(c.y, wv[4], fmaf(e.y, wv[5],
               fmaf(a.z, wv[6], fmaf(c.z, wv[7], fmaf(e.z, wv[8],
               fmaf(a.w, wv[9], fmaf(c.w, wv[10], e.w * wv[11])))))))))));
    }
}

__device__ __forceinline__ unsigned short bf16r(float x) {
    union { float f; unsigned u; } v; v.f = x;
    unsigned r = v.u + 0x7FFFu + ((v.u >> 16) & 1u);   // RNE
    return (unsigned short)(r >> 16);
}
__device__ __forceinline__ float bf16f(unsigned short h) {
    union { float f; unsigned u; } v; v.u = ((unsigned)h) << 16;
    return v.f;
}
__device__ __forceinline__ f4 unpack4(ushort4 p) {
    return make_float4(bf16f(p.x), bf16f(p.y), bf16f(p.z), bf16f(p.w));
}
__device__ __forceinline__ ushort4 pack4(f4 v) {
    ushort4 p; p.x = bf16r(v.x); p.y = bf16r(v.y);
    p.z = bf16r(v.z); p.w = bf16r(v.w); return p;
}

// block(256)=4 waves: reduce (x,y), thread 0 writes the pair to gout
__device__ __forceinline__ void red2_out(float x, float y, float* red, int tid,
                                         float* __restrict__ gout) {
#pragma unroll
    for (int off = 32; off > 0; off >>= 1) {
        x += __shfl_down(x, off, 64); y += __shfl_down(y, off, 64);
    }
    const int w = tid >> 6;
    if ((tid & 63) == 0) { red[w] = x; red[4 + w] = y; }
    __syncthreads();
    if (tid == 0) {
        gout[0] = red[0] + red[1] + red[2] + red[3];
        gout[1] = red[4] + red[5] + red[6] + red[7];
    }
}

// block(512)=8 waves: reduce + broadcast
__device__ __forceinline__ void red2_b8(float& x, float& y, float* red,
                                        float* bc, int tid) {
#pragma unroll
    for (int off = 32; off > 0; off >>= 1) {
        x += __shfl_down(x, off, 64); y += __shfl_down(y, off, 64);
    }
    const int w = tid >> 6;
    if ((tid & 63) == 0) { red[w] = x; red[8 + w] = y; }
    __syncthreads();
    if (tid == 0) {
        float sx = 0.f, sy = 0.f;
#pragma unroll
        for (int i = 0; i < 8; ++i) { sx += red[i]; sy += red[8 + i]; }
        bc[0] = sx; bc[1] = sy;
    }
    __syncthreads();
    x = bc[0]; y = bc[1];
}

// ---- K1: y1 stats from s ----
__global__ __launch_bounds__(256)
void k_stat_s(const float* __restrict__ sIn, const float* __restrict__ wd,
              float* __restrict__ outp) {
    __shared__ float red[8];
    const int tid = threadIdx.x;
    const int b = blockIdx.x >> 1;
    const int a = ((blockIdx.x & 1) << 8) | tid;
    const f4* s4 = (const f4*)sIn;
    const size_t row = ((size_t)b * 512 + a) * 64;
    const f4 z4 = make_float4(0.f, 0.f, 0.f, 0.f);
    float s1 = 0.f, s2 = 0.f;
    f4 wA = z4, wB = z4, wC = s4[row], wD = s4[row + 1], wE;
#pragma unroll 4
    for (int d = 0; d < 64; ++d) {
        wE = (d + 2 < 64) ? s4[row + d + 2] : z4;
        float y[4]; conv4(wA, wC, wE, wd, y);
#pragma unroll
        for (int o = 0; o < 4; ++o) { s1 += y[o]; s2 = fmaf(y[o], y[o], s2); }
        wA = wB; wB = wC; wC = wD; wD = wE;
    }
    red2_out(s1, s2, red, tid, outp + blockIdx.x * 2);
}

// ---- K2b/K3b: y-stats from bf16 base ----
__global__ __launch_bounds__(256)
void k_stat_b(const ushort4* __restrict__ baseB, const float* __restrict__ wd,
              float* __restrict__ outp) {
    __shared__ float red[8];
    const int tid = threadIdx.x;
    const int b = blockIdx.x >> 1;
    const int a = ((blockIdx.x & 1) << 8) | tid;
    const size_t col = (size_t)b * 32768 + a;           // + d*512
    const f4 z4 = make_float4(0.f, 0.f, 0.f, 0.f);
    float s1 = 0.f, s2 = 0.f;
    f4 wA = z4, wB = z4, wC = unpack4(baseB[col]), wD = unpack4(baseB[col + 512]), wE;
#pragma unroll 4
    for (int d = 0; d < 64; ++d) {
        wE = (d + 2 < 64) ? unpack4(baseB[col + (size_t)(d + 2) * 512]) : z4;
        float y[4]; conv4(wA, wC, wE, wd, y);
#pragma unroll
        for (int o = 0; o < 4; ++o) { s1 += y[o]; s2 = fmaf(y[o], y[o], s2); }
        wA = wB; wB = wC; wC = wD; wD = wE;
    }
    red2_out(s1, s2, red, tid, outp + blockIdx.x * 2);
}

// ---- K2: x1, base2 = s + x1 (bf16 store), t16 init, cs partials ----
__global__ __launch_bounds__(256)
void k_prod1(const float* __restrict__ sIn, const float* __restrict__ w1d,
             const float* __restrict__ w1p, const float* __restrict__ cw,
             const float* __restrict__ c2w, ushort4* __restrict__ baseB,
             float* __restrict__ t16buf, const float* __restrict__ ypIn,
             float* __restrict__ cspOut) {
    __shared__ float red[8];
    const int tid = threadIdx.x;
    const int b = blockIdx.x >> 1;
    const int a = ((blockIdx.x & 1) << 8) | tid;
    const f4* s4 = (const f4*)sIn;
    const size_t row = ((size_t)b * 512 + a) * 64;
    const size_t col = (size_t)b * 32768 + a;
    const f4 z4 = make_float4(0.f, 0.f, 0.f, 0.f);
    const float NY = 131072.f;
    const float p0 = ypIn[(b * 2) * 2] + ypIn[(b * 2 + 1) * 2];
    const float q0 = ypIn[(b * 2) * 2 + 1] + ypIn[(b * 2 + 1) * 2 + 1];
    const float m1 = p0 / NY;
    const float r1 = rsqrtf(q0 / NY - m1 * m1 + EPS_LN);

    float t16a[16];
#pragma unroll
    for (int o = 0; o < 16; ++o) t16a[o] = 0.f;
    float cs1 = 0.f, cs2 = 0.f;

    f4 wA = z4, wB = z4, wC = s4[row], wD = s4[row + 1], wE;
#pragma unroll 4
    for (int d = 0; d < 64; ++d) {
        wE = (d + 2 < 64) ? s4[row + d + 2] : z4;
        float y[4]; conv4(wA, wC, wE, w1d, y);
        float g[4];
#pragma unroll
        for (int o = 0; o < 4; ++o) {
            y[o] = (y[o] - m1) * r1;
        }
#pragma unroll
        for (int o = 0; o < 4; ++o) {
            float zz = fmaf(y[0], w1p[o*4+0], fmaf(y[1], w1p[o*4+1],
                       fmaf(y[2], w1p[o*4+2], y[3] * w1p[o*4+3])));
            g[o] = gelu_f(zz);
            cs1 += g[o]; cs2 = fmaf(g[o], g[o], cs2);
        }
        f4 nb = make_float4(wC.x + g[0], wC.y + g[1], wC.z + g[2], wC.w + g[3]);
        baseB[col + (size_t)d * 512] = pack4(nb);
        float u[4];
#pragma unroll
        for (int co = 0; co < 4; ++co)
            u[co] = fmaf(g[0], cw[co*12+0], fmaf(g[1], cw[co*12+1],
                    fmaf(g[2], cw[co*12+2], g[3] * cw[co*12+3])));
#pragma unroll
        for (int o = 0; o < 16; ++o) {
            const float* p = c2w + o * 256 + d;
            t16a[o] = fmaf(u[0], p[0], fmaf(u[1], p[64],
                      fmaf(u[2], p[128], fmaf(u[3], p[192], t16a[o]))));
        }
        wA = wB; wB = wC; wC = wD; wD = wE;
    }
    float* tp = t16buf + ((size_t)b * 512 + a) * 16;
#pragma unroll
    for (int o = 0; o < 16; ++o) tp[o] = t16a[o];
    red2_out(cs1, cs2, red, tid, cspOut + blockIdx.x * 2);
}

// ---- K3/K4: x2 (write base3 in-place) / x3 (no base write); t16 RMW ----
__global__ __launch_bounds__(256)
void k_prod23(ushort4* __restrict__ baseB, const float* __restrict__ wd,
              const float* __restrict__ wp, const float* __restrict__ cw,
              const float* __restrict__ c2w, float* __restrict__ t16buf,
              const float* __restrict__ ypIn, float* __restrict__ cspOut,
              const int cwOff, const int writeBase) {
    __shared__ float red[8];
    const int tid = threadIdx.x;
    const int b = blockIdx.x >> 1;
    const int a = ((blockIdx.x & 1) << 8) | tid;
    const size_t col = (size_t)b * 32768 + a;
    const f4 z4 = make_float4(0.f, 0.f, 0.f, 0.f);
    const float NY = 131072.f;
    const float p0 = ypIn[(b * 2) * 2] + ypIn[(b * 2 + 1) * 2];
    const float q0 = ypIn[(b * 2) * 2 + 1] + ypIn[(b * 2 + 1) * 2 + 1];
    const float mS = p0 / NY;
    const float rS = rsqrtf(q0 / NY - mS * mS + EPS_LN);

    float t16a[16];
    float* tp = t16buf + ((size_t)b * 512 + a) * 16;
#pragma unroll
    for (int o = 0; o < 16; ++o) t16a[o] = tp[o];
    float cs1 = 0.f, cs2 = 0.f;

    f4 wA = z4, wB = z4, wC = unpack4(baseB[col]), wD = unpack4(baseB[col + 512]), wE;
#pragma unroll 4
    for (int d = 0; d < 64; ++d) {
        wE = (d + 2 < 64) ? unpack4(baseB[col + (size_t)(d + 2) * 512]) : z4;
        float y[4]; conv4(wA, wC, wE, wd, y);
        float g[4];
#pragma unroll
        for (int o = 0; o < 4; ++o) y[o] = (y[o] - mS) * rS;
#pragma unroll
        for (int o = 0; o < 4; ++o) {
            float zz = fmaf(y[0], wp[o*4+0], fmaf(y[1], wp[o*4+1],
                       fmaf(y[2], wp[o*4+2], y[3] * wp[o*4+3])));
            g[o] = gelu_f(zz);
            cs1 += g[o]; cs2 = fmaf(g[o], g[o], cs2);
        }
        if (writeBase) {   // base3 = base2 + x2; in-place safe: pos d was read at iter d-2
            f4 nb = make_float4(wC.x + g[0], wC.y + g[1], wC.z + g[2], wC.w + g[3]);
            baseB[col + (size_t)d * 512] = pack4(nb);
        }
        float u[4];
#pragma unroll
        for (int co = 0; co < 4; ++co)
            u[co] = fmaf(g[0], cw[co*12+cwOff+0], fmaf(g[1], cw[co*12+cwOff+1],
                    fmaf(g[2], cw[co*12+cwOff+2], g[3] * cw[co*12+cwOff+3])));
#pragma unroll
        for (int o = 0; o < 16; ++o) {
            const float* p = c2w + o * 256 + d;
            t16a[o] = fmaf(u[0], p[0], fmaf(u[1], p[64],
                      fmaf(u[2], p[128], fmaf(u[3], p[192], t16a[o]))));
        }
        wA = wB; wB = wC; wC = wD; wD = wE;
    }
#pragma unroll
    for (int o = 0; o < 16; ++o) tp[o] = t16a[o];
    red2_out(cs1, cs2, red, tid, cspOut + blockIdx.x * 2);
}

// ---- K5: tail (concat-LN affine on t16, LN16, c3w+w, LN-A) ----
__global__ __launch_bounds__(512)
void k_tail(const float* __restrict__ wIn, const float* __restrict__ cw,
            const float* __restrict__ c2w, const float* __restrict__ c3w,
            const float* __restrict__ t16buf, const float* __restrict__ csp,
            float* __restrict__ out) {
    __shared__ float red[16];
    __shared__ float bc[2];
    __shared__ float Klds[16];
    const int b = blockIdx.x;
    const int tid = threadIdx.x;          // == a

    if (tid < 16) {
        float k = 0.f;
        for (int co = 0; co < 4; ++co) {
            float csum = 0.f;
            for (int j = 0; j < 12; ++j) csum += cw[co * 12 + j];
            const float* p = c2w + tid * 256 + co * 64;
            float t = 0.f;
            for (int d = 0; d < 64; ++d) t += p[d];
            k = fmaf(csum, t, k);
        }
        Klds[tid] = k;
    }
    __syncthreads();

    float cs1 = 0.f, cs2 = 0.f;
#pragma unroll
    for (int ph = 0; ph < 3; ++ph)
#pragma unroll
        for (int c = 0; c < 2; ++c) {
            cs1 += csp[ph * 1024 + (b * 2 + c) * 2];
            cs2 += csp[ph * 1024 + (b * 2 + c) * 2 + 1];
        }
    const float NC = 393216.f;
    const float mcat = cs1 / NC;
    const float rcat = rsqrtf(cs2 / NC - mcat * mcat + EPS_LN);

    const float* tp = t16buf + ((size_t)b * 512 + tid) * 16;
    float tv[16];
    float p1 = 0.f, p2 = 0.f;
#pragma unroll
    for (int o = 0; o < 16; ++o) {
        float v = rcat * (tp[o] - mcat * Klds[o]);
        tv[o] = v; p1 += v; p2 = fmaf(v, v, p2);
    }
    red2_b8(p1, p2, red, bc, tid);
    const float m16 = p1 / 8192.f;
    const float r16 = rsqrtf(p2 / 8192.f - m16 * m16 + EPS_LN);

    float v = wIn[(size_t)b * 512 + tid] * c3w[16];
#pragma unroll
    for (int o = 0; o < 16; ++o) v = fmaf((tv[o] - m16) * r16, c3w[o], v);
    float f1 = v, f2 = v * v;
    red2_b8(f1, f2, red, bc, tid);
    const float mA = f1 / 512.f;
    const float rA = rsqrtf(f2 / 512.f - mA * mA + EPS_LN);

    out[(size_t)b * 512 + tid] = (v - mA) * rA;
}

extern "C" void kernel_launch(void* const* d_in, const int* in_sizes, int n_in,
                              void* d_out, int out_size, void* d_ws, size_t ws_size,
                              hipStream_t stream) {
    const float* s   = (const float*)d_in[0];
    const float* w   = (const float*)d_in[1];
    const float* w1d = (const float*)d_in[2];
    const float* w1p = (const float*)d_in[3];
    const float* w2d = (const float*)d_in[4];
    const float* w2p = (const float*)d_in[5];
    const float* w3d = (const float*)d_in[6];
    const float* w3p = (const float*)d_in[7];
    const float* cw  = (const float*)d_in[8];
    const float* c2w = (const float*)d_in[9];
    const float* c3w = (const float*)d_in[10];

    char* ws = (char*)d_ws;
    ushort4* baseB  = (ushort4*)ws;                              // 64 MiB
    float*   t16buf = (float*)(ws + 67108864);                   // 8 MiB
    float*   stats  = (float*)(ws + 67108864 + 8388608);         // 24 KiB
    float*   y1p = stats;                                        // 1024 f
    float*   y2p = stats + 1024;
    float*   y3p = stats + 2048;
    float*   csp = stats + 3072;                                 // 3*1024 f

    dim3 g(512), blk(256);
    k_stat_s<<<g, blk, 0, stream>>>(s, w1d, y1p);
    k_prod1 <<<g, blk, 0, stream>>>(s, w1d, w1p, cw, c2w, baseB, t16buf, y1p, csp);
    k_stat_b<<<g, blk, 0, stream>>>(baseB, w2d, y2p);
    k_prod23<<<g, blk, 0, stream>>>(baseB, w2d, w2p, cw, c2w, t16buf, y2p, csp + 1024, 4, 1);
    k_stat_b<<<g, blk, 0, stream>>>(baseB, w3d, y3p);
    k_prod23<<<g, blk, 0, stream>>>(baseB, w3d, w3p, cw, c2w, t16buf, y3p, csp + 2048, 8, 0);
    k_tail  <<<dim3(256), dim3(512), 0, stream>>>(w, cw, c2w, c3w, t16buf, csp, (float*)d_out);
}